// Round 3
// baseline (272.950 us; speedup 1.0000x reference)
//
#include <hip/hip_runtime.h>

#define BLOCK 256

// ---- compile-time chemistry tables ----
// COMMON_AM = [0,0,1,2]
constexpr int LSLOTc[4]   = {0,0,1,2};           // l of each slot
constexpr int DSLOTc[4]   = {1,1,3,5};           // 2l+1 of each slot
// feature offset of block (s1,s2) within the 100-dim edge feature (row-major over slots)
constexpr int OFFTABc[16] = {0,1,2,5,10,11,12,15,20,23,26,35,50,55,60,75};
constexpr int ROFF0c[4]   = {0,0,1,0};           // row/col offset by slot, type0 (valid slots 0,2)
constexpr int ROFF1c[4]   = {0,1,2,5};           // row/col offset by slot, type1

struct CgPtrs { const float* p[9]; };            // p[l1*3+l2]
struct Desc   { int b0, b1, b2, b3, n01, n10, q, s00, s01, s10, s11; };

// Accumulate one (S1,S2) sub-block of one edge into the band accumulator.
template<int T1, int S1, int T2, int S2, int NACC>
__device__ __forceinline__ void band_block(
    const float* __restrict__ xr, const float* __restrict__ yr,
    const float* __restrict__ xn, const float* __restrict__ yn,
    bool selfx, bool selfy, const CgPtrs& cg, float (&acc)[NACC])
{
    constexpr int l1   = LSLOTc[S1], l2 = LSLOTc[S2];
    constexpr int d1   = DSLOTc[S1], d2 = DSLOTc[S2];
    constexpr int K    = d1 * d2;
    constexpr int off1 = OFFTABc[4 * S1 + S2];
    constexpr int off2 = OFFTABc[4 * S2 + S1];
    constexpr int DIM2 = T2 ? 10 : 4;
    constexpr int coff = T2 ? ROFF1c[S2] : ROFF0c[S2];

    const float* __restrict__ cgA = cg.p[l1 * 3 + l2];   // cg_{l1,l2}[i][j][k]
    const float* __restrict__ cgB = cg.p[l2 * 3 + l1];   // cg_{l2,l1}[j][i][k]

    float x[K], y[K];
    #pragma unroll
    for (int k = 0; k < K; ++k) x[k] = xr[off1 + k];
    if (selfx) {
        #pragma unroll
        for (int k = 0; k < K; ++k) x[k] += xn[off1 + k];
    }
    #pragma unroll
    for (int k = 0; k < K; ++k) y[k] = yr[off2 + k];
    if (selfy) {
        #pragma unroll
        for (int k = 0; k < K; ++k) y[k] += yn[off2 + k];
    }

    #pragma unroll
    for (int i = 0; i < d1; ++i) {
        #pragma unroll
        for (int k = 0; k < K; ++k) {
            #pragma unroll
            for (int j = 0; j < d2; ++j) {
                acc[i * DIM2 + coff + j] = fmaf(x[k], cgA[(i * d2 + j) * K + k], acc[i * DIM2 + coff + j]);
                acc[i * DIM2 + coff + j] = fmaf(y[k], cgB[(j * d1 + i) * K + k], acc[i * DIM2 + coff + j]);
            }
        }
    }
}

// One thread = one (edge, S1-band). Band rows are contiguous in the output row.
template<int T1, int S1, int T2>
__device__ __forceinline__ void ham_band(
    int ib, int s, const int* __restrict__ sel,
    const float* __restrict__ fn, const float* __restrict__ fe,
    const float* __restrict__ S, const int* __restrict__ n1,
    const int* __restrict__ n2, const int* __restrict__ inv,
    const CgPtrs& cg, float* __restrict__ o)
{
    if (ib >= s) return;
    constexpr int DIM1 = T1 ? 10 : 4;
    constexpr int DIM2 = T2 ? 10 : 4;
    constexpr int RC   = DIM1 * DIM2;
    constexpr int d1   = DSLOTc[S1];
    constexpr int roff = T1 ? ROFF1c[S1] : ROFF0c[S1];

    const int e  = sel[ib];
    const int ei = inv[e];
    const int ax = n1[e],  bx = n2[e];
    const int ay = n1[ei], by = n2[ei];
    const float sx0 = S[3 * e],  sx1 = S[3 * e + 1],  sx2 = S[3 * e + 2];
    const float sy0 = S[3 * ei], sy1 = S[3 * ei + 1], sy2 = S[3 * ei + 2];
    const bool selfx = (ax == bx) && (sx0 * sx0 + sx1 * sx1 + sx2 * sx2 < 1e-12f);
    const bool selfy = (ay == by) && (sy0 * sy0 + sy1 * sy1 + sy2 * sy2 < 1e-12f);

    const float* __restrict__ xr = fe + (size_t)e  * 100;
    const float* __restrict__ yr = fe + (size_t)ei * 100;
    const float* __restrict__ xn = fn + (size_t)ax * 100;
    const float* __restrict__ yn = fn + (size_t)ay * 100;

    float acc[d1 * DIM2];
    #pragma unroll
    for (int u = 0; u < d1 * DIM2; ++u) acc[u] = 0.f;

    band_block<T1, S1, T2, 0>(xr, yr, xn, yn, selfx, selfy, cg, acc);
    if constexpr (T2 == 0) {
        band_block<T1, S1, T2, 2>(xr, yr, xn, yn, selfx, selfy, cg, acc);
    } else {
        band_block<T1, S1, T2, 1>(xr, yr, xn, yn, selfx, selfy, cg, acc);
        band_block<T1, S1, T2, 2>(xr, yr, xn, yn, selfx, selfy, cg, acc);
        band_block<T1, S1, T2, 3>(xr, yr, xn, yn, selfx, selfy, cg, acc);
    }

    float* __restrict__ orow = o + (size_t)ib * RC + roff * DIM2;
    #pragma unroll
    for (int u = 0; u < d1 * DIM2; ++u) orow[u] = 0.5f * acc[u];
}

#define HB_ARGS fn, fe, S, n1, n2, inv, cg

// type0 rows: 2 bands x 128 edges per block (wave-uniform band select)
template<int T2>
__device__ __forceinline__ void seg_type0(
    int blk, int tid, int s, const int* __restrict__ sel,
    const float* __restrict__ fn, const float* __restrict__ fe,
    const float* __restrict__ S, const int* __restrict__ n1,
    const int* __restrict__ n2, const int* __restrict__ inv,
    const CgPtrs& cg, float* __restrict__ o)
{
    const int lane = tid & 127;
    const int band = tid >> 7;
    const int ib   = blk * 128 + lane;
    if (band == 0) ham_band<0, 0, T2>(ib, s, sel, HB_ARGS, o);
    else           ham_band<0, 2, T2>(ib, s, sel, HB_ARGS, o);
}

// type1 rows: 4 bands x 64 edges per block (wave-uniform band select)
template<int T2>
__device__ __forceinline__ void seg_type1(
    int blk, int tid, int s, const int* __restrict__ sel,
    const float* __restrict__ fn, const float* __restrict__ fe,
    const float* __restrict__ S, const int* __restrict__ n1,
    const int* __restrict__ n2, const int* __restrict__ inv,
    const CgPtrs& cg, float* __restrict__ o)
{
    const int lane = tid & 63;
    const int band = tid >> 6;
    const int ib   = blk * 64 + lane;
    if      (band == 0) ham_band<1, 0, T2>(ib, s, sel, HB_ARGS, o);
    else if (band == 1) ham_band<1, 1, T2>(ib, s, sel, HB_ARGS, o);
    else if (band == 2) ham_band<1, 2, T2>(ib, s, sel, HB_ARGS, o);
    else                ham_band<1, 3, T2>(ib, s, sel, HB_ARGS, o);
}

__global__ __launch_bounds__(BLOCK, 3) void fused_kernel(
    const float* __restrict__ fn, const float* __restrict__ fe,
    const float* __restrict__ S, const int* __restrict__ n1,
    const int* __restrict__ n2, const int* __restrict__ inv,
    const int* __restrict__ sel00, const int* __restrict__ sel01,
    const int* __restrict__ sel10, const int* __restrict__ sel11,
    CgPtrs cg, Desc d, float* __restrict__ out)
{
    float* o00 = out;
    float* o01 = o00 + (size_t)d.s00 * 16;
    float* o10 = o01 + (size_t)d.s01 * 40;
    float* o11 = o10 + (size_t)d.s10 * 40;
    float* og  = o11 + (size_t)d.s11 * 100;

    const int bid = blockIdx.x;
    const int tid = threadIdx.x;

    if (bid < d.b0) {                       // segment <0,0>
        seg_type0<0>(bid, tid, d.s00, sel00, HB_ARGS, o00);
        return;
    }
    if (bid < d.b1) {                       // segments <0,1> and <1,0>, interleaved 1:2
        const int r = bid - d.b0;
        int which, blk;
        if (r < 3 * d.q) {
            const int g = r / 3, m = r % 3;
            if (m == 0) { which = 0; blk = g; }
            else        { which = 1; blk = 2 * g + (m - 1); }
        } else {
            const int t     = r - 3 * d.q;
            const int rem01 = d.n01 - d.q;
            if (t < rem01) { which = 0; blk = d.q + t; }
            else           { which = 1; blk = 2 * d.q + (t - rem01); }
        }
        if (which == 0) seg_type0<1>(blk, tid, d.s01, sel01, HB_ARGS, o01);
        else            seg_type1<0>(blk, tid, d.s10, sel10, HB_ARGS, o10);
        return;
    }
    if (bid < d.b2) {                       // segment <1,1>
        seg_type1<1>(bid - d.b1, tid, d.s11, sel11, HB_ARGS, o11);
        return;
    }
    // segment g2b (float-encoded indices; counts < 2^24 so exact)
    {
        int u = (bid - d.b2) * BLOCK + tid;
        if (u < d.s00) { og[sel00[u]] = (float)u; return; }  u -= d.s00;
        if (u < d.s01) { og[sel01[u]] = (float)u; return; }  u -= d.s01;
        if (u < d.s10) { og[sel10[u]] = (float)u; return; }  u -= d.s10;
        if (u < d.s11) { og[sel11[u]] = (float)u; return; }
    }
}

extern "C" void kernel_launch(void* const* d_in, const int* in_sizes, int n_in,
                              void* d_out, int out_size, void* d_ws, size_t ws_size,
                              hipStream_t stream)
{
    const float* fn  = (const float*)d_in[0];
    const float* fe  = (const float*)d_in[1];
    const float* S   = (const float*)d_in[2];
    const int*  eidx = (const int*)d_in[3];
    const int*  inv  = (const int*)d_in[5];
    CgPtrs cg;
    for (int i = 0; i < 9; ++i) cg.p[i] = (const float*)d_in[6 + i];
    const int* sel00 = (const int*)d_in[15];
    const int* sel01 = (const int*)d_in[16];
    const int* sel10 = (const int*)d_in[17];
    const int* sel11 = (const int*)d_in[18];

    const int E   = in_sizes[3] / 2;
    const int* n1 = eidx;
    const int* n2 = eidx + E;

    Desc d;
    d.s00 = in_sizes[15]; d.s01 = in_sizes[16]; d.s10 = in_sizes[17]; d.s11 = in_sizes[18];
    const int tot = d.s00 + d.s01 + d.s10 + d.s11;

    const int n00 = (d.s00 + 127) / 128;
    d.n01 = (d.s01 + 127) / 128;
    d.n10 = (d.s10 + 63)  / 64;
    const int n11 = (d.s11 + 63) / 64;
    const int ngb = (tot + BLOCK - 1) / BLOCK;
    d.q = d.n01 < (d.n10 / 2) ? d.n01 : (d.n10 / 2);

    d.b0 = n00;
    d.b1 = d.b0 + d.n01 + d.n10;
    d.b2 = d.b1 + n11;
    d.b3 = d.b2 + ngb;

    if (d.b3 > 0)
        fused_kernel<<<d.b3, BLOCK, 0, stream>>>(
            fn, fe, S, n1, n2, inv, sel00, sel01, sel10, sel11,
            cg, d, (float*)d_out);
}